// Round 1
// baseline (1175.707 us; speedup 1.0000x reference)
//
#include <hip/hip_runtime.h>
#include <cmath>

typedef unsigned int u32;
typedef unsigned long long u64;

#define NLEV 5
#define M_TOT 4900
#define NWORDS 77          // ceil(4900/64)
#define CSTRIDE 80         // cmat row stride in u64 words (640B)
#define CAP 131072         // candidate capacity per level
#define PAD_M 4928

__constant__ int   c_KLVL[5] = {1000,1000,1000,1000,900};
__constant__ int   c_LOFF[5] = {0,1000,2000,3000,4000};
__constant__ int   c_PR[6]   = {0,18432000,23040000,24192000,24480000,24552000};
__constant__ float c_THR[5]  = {1.0f,0.65f,0.30f,-0.15f,-0.60f};

// ---- workspace layout (bytes) ----
constexpr size_t OFF_CNT   = 0;       // u32[8]  per-level candidate counts
constexpr size_t OFF_FLAG  = 64;      // u32[8]  fallback flags
constexpr size_t OFF_KEPT  = 256;     // u64[80] keep bitmask
constexpr size_t OFF_UNDEC = 1024;    // u64[80] undecided bitmask
constexpr size_t ZERO_BYTES= 4096;
constexpr size_t OFF_CAND  = 4096;                               // u32[5*CAP*2]
constexpr size_t OFF_KEY   = OFF_CAND + (size_t)NLEV*CAP*8;      // u64[PAD_M]
constexpr size_t OFF_RAWB  = OFF_KEY   + (size_t)PAD_M*8;        // float4[PAD_M]
constexpr size_t OFF_OFFB  = OFF_RAWB  + (size_t)PAD_M*16;
constexpr size_t OFF_LAB   = OFF_OFFB  + (size_t)PAD_M*16;       // u32
constexpr size_t OFF_SVAL  = OFF_LAB   + (size_t)PAD_M*4;        // f32
constexpr size_t OFF_VALID = OFF_SVAL  + (size_t)PAD_M*4;        // u32
constexpr size_t OFF_ORDER = OFF_VALID + (size_t)PAD_M*4;        // u32
constexpr size_t OFF_SRAWB = OFF_ORDER + (size_t)PAD_M*4;        // float4
constexpr size_t OFF_SOFFB = OFF_SRAWB + (size_t)PAD_M*16;
constexpr size_t OFF_SLAB  = OFF_SOFFB + (size_t)PAD_M*16;       // u32
constexpr size_t OFF_SSVAL = OFF_SLAB  + (size_t)PAD_M*4;        // f32
constexpr size_t OFF_SVALID= OFF_SSVAL + (size_t)PAD_M*4;        // u32
constexpr size_t OFF_CEMPTY= OFF_SVALID+ (size_t)PAD_M*4;        // u32
constexpr size_t OFF_CMAT  = (OFF_CEMPTY + (size_t)PAD_M*4 + 255) & ~(size_t)255;

__device__ __forceinline__ u32 okey(u32 u){
  return (u & 0x80000000u) ? ~u : (u | 0x80000000u);
}

// ---------------- candidate collection (streaming pass over logits) --------
__global__ void __launch_bounds__(256)
k_collect(const float* __restrict__ a0, const float* __restrict__ a1,
          const float* __restrict__ a2, const float* __restrict__ a3,
          const float* __restrict__ a4,
          u32* __restrict__ cnt, u32* __restrict__ cand,
          const u32* __restrict__ flags, int round)
{
  bool part[5]; float thr[5]; bool anyp=false;
#pragma unroll
  for (int l=0;l<5;l++){
    part[l] = (round==0) || (flags[l]!=0u);
    anyp = anyp || part[l];
    thr[l] = c_THR[l] - 0.8f*(float)round;
  }
  if (!anyp) return;
  const float* cls[5]={a0,a1,a2,a3,a4};
  int total4 = c_PR[5]/4;
  int stride = gridDim.x*blockDim.x;
  for (int q=blockIdx.x*blockDim.x+threadIdx.x; q<total4; q+=stride){
    int e=q*4;
    int l = (e<c_PR[1])?0:(e<c_PR[2])?1:(e<c_PR[3])?2:(e<c_PR[4])?3:4;
    if (!part[l]) continue;
    int local = e - c_PR[l];
    const float4 x4 = *(const float4*)(cls[l]+local);
    float xs[4]={x4.x,x4.y,x4.z,x4.w};
    float T=thr[l];
#pragma unroll
    for (int i=0;i<4;i++){
      if (xs[i]>T){
        u32 p=atomicAdd(&cnt[l],1u);
        if (p<CAP){
          u32* dst=cand+((size_t)l*CAP+(size_t)p)*2u;
          dst[0]=__float_as_uint(xs[i]);
          dst[1]=(u32)(local+i);
        }
      }
    }
  }
}

__global__ void k_fbmark(u32* cnt, u32* flags){
  int t=threadIdx.x;
  if (t<5){
    u32 need=(cnt[t]<(u32)c_KLVL[t])?1u:0u;
    flags[t]=need;
    if (need) cnt[t]=0u;
  }
}

// ---------------- per-level exact top-k (radix select) + record emit -------
__device__ __forceinline__ void emit_record(int l, int slot, u32 lbits, u32 idx,
    const float4* __restrict__ boxp, u64* keyA, float4* rawbA, float4* offbA,
    u32* labA, float* svalA, u32* validA)
{
#pragma clang fp contract(off)
  float x = __uint_as_float(lbits);
  float s = (float)(1.0 / (1.0 + exp(-(double)x)));
  u32 valid = (s > 0.05f) ? 1u : 0u;
  u32 label = idx % 80u;
  u32 anchor = idx / 80u;
  float4 bx = boxp[anchor];
  float off = (float)label * 1281.0f;   // label * (IMG + 1)
  float4 ob;
  ob.x = bx.x + off; ob.y = bx.y + off; ob.z = bx.z + off; ob.w = bx.w + off;
  u32 pos = ((u32)l << 25) | idx;
  u32 khi = valid ? okey(lbits) : 0u;
  int g = c_LOFF[l] + slot;
  keyA[g]  = ((u64)khi << 32) | (u64)(u32)(~pos);
  rawbA[g] = bx; offbA[g] = ob; labA[g] = label;
  svalA[g] = valid ? s : 0.0f; validA[g] = valid;
}

__device__ __forceinline__ void emit_dummy(int l, int slot,
    u64* keyA, float4* rawbA, float4* offbA, u32* labA, float* svalA, u32* validA)
{
  u32 pos = ((u32)l<<25) | (0x1FFFFFFu - (u32)slot);  // beyond any real idx -> unique
  int g = c_LOFF[l]+slot;
  float4 z; z.x=z.y=z.z=z.w=0.0f;
  keyA[g]=(u64)(u32)(~pos);
  rawbA[g]=z; offbA[g]=z; labA[g]=0u; svalA[g]=0.0f; validA[g]=0u;
}

__global__ void __launch_bounds__(1024)
k_select(const u32* __restrict__ cnt, const u32* __restrict__ cand,
         const float4* b0, const float4* b1, const float4* b2,
         const float4* b3, const float4* b4,
         u64* keyA, float4* rawbA, float4* offbA,
         u32* labA, float* svalA, u32* validA)
{
  const int l = blockIdx.x;
  const float4* boxp = (l==0)?b0:(l==1)?b1:(l==2)?b2:(l==3)?b3:b4;
  const u32* cd = cand + (size_t)l*CAP*2u;
  const int k = c_KLVL[l];
  int count = (int)min(cnt[l], (u32)CAP);

  __shared__ u32 hist[256];
  __shared__ u32 selv, selab;
  __shared__ u32 ntie_s, emit_s;
  __shared__ u32 tieIdx[1024];

  u32 prefix=0u, pmask=0u;
  int kk = (count < k) ? count : k;

  if (count > 0){
    for (int r=0;r<4;r++){
      int shift = 24 - 8*r;
      if (threadIdx.x<256) hist[threadIdx.x]=0u;
      __syncthreads();
      for (int i=threadIdx.x;i<count;i+=1024){
        u32 key = okey(cd[2*(size_t)i]);
        if ((key & pmask)==prefix) atomicAdd(&hist[(key>>shift)&255u],1u);
      }
      __syncthreads();
      if (threadIdx.x<256){
        u32 above=0u;
        for (int v=threadIdx.x+1; v<256; v++) above+=hist[v];
        u32 h=hist[threadIdx.x];
        if ((int)above < kk && kk <= (int)(above+h)){ selv=(u32)threadIdx.x; selab=above; }
      }
      __syncthreads();
      prefix |= selv<<shift; pmask |= 255u<<shift; kk -= (int)selab;
      __syncthreads();
    }
  }
  if (threadIdx.x==0){ ntie_s=0u; emit_s=0u; }
  __syncthreads();

  for (int i=threadIdx.x;i<count;i+=1024){
    u32 lb = cd[2*(size_t)i]; u32 idx = cd[2*(size_t)i+1];
    u32 key = okey(lb);
    if (key > prefix){
      u32 s = atomicAdd(&emit_s,1u);
      if ((int)s < k) emit_record(l,(int)s,lb,idx,boxp,keyA,rawbA,offbA,labA,svalA,validA);
    } else if (key == prefix){
      u32 t = atomicAdd(&ntie_s,1u);
      if (t < 1024u) tieIdx[t]=idx;
    }
  }
  __syncthreads();

  u32 tie_lbits = (prefix & 0x80000000u) ? (prefix ^ 0x80000000u) : ~prefix;
  int nt = (int)min(ntie_s,1024u);
  for (int t=threadIdx.x;t<nt;t+=1024){
    u32 my = tieIdx[t];
    int rank=0;
    for (int t2=0;t2<nt;t2++) rank += (tieIdx[t2] < my) ? 1 : 0;
    if (rank < kk){
      u32 s = atomicAdd(&emit_s,1u);
      if ((int)s<k) emit_record(l,(int)s,tie_lbits,my,boxp,keyA,rawbA,offbA,labA,svalA,validA);
    }
  }
  __syncthreads();
  int em = (int)min(emit_s,(u32)k);
  for (int i=em+threadIdx.x;i<k;i+=1024)
    emit_dummy(l,i,keyA,rawbA,offbA,labA,svalA,validA);
}

// ---------------- global sort via rank-by-counting (keys unique) -----------
__global__ void __launch_bounds__(1024)
k_rank(const u64* __restrict__ keyA, u32* __restrict__ order){
  __shared__ u64 sk[M_TOT];
  for (int i=threadIdx.x;i<M_TOT;i+=1024) sk[i]=keyA[i];
  __syncthreads();
  int t = blockIdx.x*1024+threadIdx.x;
  if (t<M_TOT){
    u64 mk = sk[t];
    int r=0;
#pragma unroll 4
    for (int j=0;j<M_TOT;j++) r += (sk[j]>mk)?1:0;
    order[r]=(u32)t;
  }
}

__global__ void k_gather(const u32* __restrict__ order,
    const float4* __restrict__ rawbA, const float4* __restrict__ offbA,
    const u32* __restrict__ labA, const float* __restrict__ svalA,
    const u32* __restrict__ validA,
    float4* srawb, float4* soffb, u32* slab, float* ssval, u32* svalid)
{
  int t=blockIdx.x*blockDim.x+threadIdx.x;
  if (t<M_TOT){
    u32 slot=min(order[t],(u32)(M_TOT-1));
    srawb[t]=rawbA[slot]; soffb[t]=offbA[slot]; slab[t]=labA[slot];
    ssval[t]=svalA[slot]; svalid[t]=validA[slot];
  }
}

// ---------------- predecessor bitmask matrix (column-major) ----------------
__global__ void __launch_bounds__(256)
k_cmat(const float4* __restrict__ soffb, u64* __restrict__ cmat,
       u32* __restrict__ cempty)
{
#pragma clang fp contract(off)
  int j = blockIdx.x;
  int lane = threadIdx.x & 63;
  int wave = threadIdx.x >> 6;
  __shared__ u32 anyb;
  if (threadIdx.x==0) anyb=0u;
  __syncthreads();
  float4 bj = soffb[j];
  float areaJ = fmaxf(bj.z-bj.x,0.0f)*fmaxf(bj.w-bj.y,0.0f);
  int wmax = j>>6;
  u32 lany=0u;
  for (int w=wave; w<NWORDS; w+=4){
    u64 word=0ull;
    if (w<=wmax){
      int row=w*64+lane;
      bool bit=false;
      if (row<j){
        float4 br = soffb[row];
        float areaR = fmaxf(br.z-br.x,0.0f)*fmaxf(br.w-br.y,0.0f);
        float ltx=fmaxf(br.x,bj.x), lty=fmaxf(br.y,bj.y);
        float rbx=fminf(br.z,bj.z), rby=fminf(br.w,bj.w);
        float wx=fmaxf(rbx-ltx,0.0f), wy=fmaxf(rby-lty,0.0f);
        float inter=wx*wy;
        float den = areaR+areaJ-inter+1e-9f;   // matches ref eval order
        float iou = inter/den;
        bit = iou > 0.6f;
      }
      word = __ballot(bit);
    }
    if (lane==0) cmat[(size_t)j*CSTRIDE+(size_t)w]=word;
    if (word) lany=1u;
  }
  if (lany) atomicOr(&anyb,1u);
  __syncthreads();
  if (threadIdx.x==0) cempty[j] = (anyb==0u)?1u:0u;
}

__global__ void k_init(const u32* __restrict__ cempty, const u32* __restrict__ svalid,
                       u64* kept, u64* undec)
{
  int t=blockIdx.x*blockDim.x+threadIdx.x;
  if (t<M_TOT){
    if (cempty[t]){ if (svalid[t]) atomicOr(&kept[t>>6], 1ull<<(t&63)); }
    else atomicOr(&undec[t>>6], 1ull<<(t&63));
  }
}

// ---------------- sequential greedy resolution of undecided nodes ---------
__global__ void __launch_bounds__(64)
k_scan(const u64* __restrict__ cmat, const u64* __restrict__ undec,
       const u32* __restrict__ svalid, u64* __restrict__ kept)
{
  __shared__ u32 list[M_TOT];
  __shared__ u32 n_s;
  __shared__ u64 uw[NWORDS];
  int lane = threadIdx.x;
  uw[lane]=undec[lane];
  if (lane<NWORDS-64) uw[64+lane]=undec[64+lane];
  __syncthreads();
  if (lane==0){
    u32 n=0;
    for (int w=0;w<NWORDS;w++){
      u64 U=uw[w];
      while(U){ int b=__builtin_ctzll(U); U&=U-1ull; list[n++]=(u32)(w*64+b); }
    }
    n_s=n;
  }
  __syncthreads();
  u32 n=n_s;
  u64 kw0=kept[lane];
  u64 kw1=(lane<NWORDS-64)?kept[64+lane]:0ull;

  u64 ca[4], cb[4]; u32 vv[4];
#pragma unroll
  for (int i=0;i<4;i++){
    ca[i]=0ull; cb[i]=0ull; vv[i]=0u;
    if ((u32)i<n){
      u32 j=list[i]; const u64* cp=cmat+(size_t)j*CSTRIDE;
      ca[i]=cp[lane]; cb[i]=(lane<NWORDS-64)?cp[64+lane]:0ull; vv[i]=svalid[j];
    }
  }
  for (u32 base=0; base<n; base+=4){
#pragma unroll
    for (int i=0;i<4;i++){
      u32 t=base+(u32)i;
      if (t>=n) break;
      u64 c0=ca[i], c1=cb[i]; u32 v=vv[i]; u32 j=list[t];
      u32 tp=t+4;
      if (tp<n){
        u32 j2=list[tp]; const u64* cp=cmat+(size_t)j2*CSTRIDE;
        ca[i]=cp[lane]; cb[i]=(lane<NWORDS-64)?cp[64+lane]:0ull; vv[i]=svalid[j2];
      } else { ca[i]=0ull; cb[i]=0ull; vv[i]=0u; }
      int hit = (((c0&kw0)|(c1&kw1))!=0ull)?1:0;
      bool any = __ballot(hit)!=0ull;
      if (!any && v){
        u32 w=j>>6, b=j&63u;
        if (w<64u){ if ((u32)lane==w) kw0|=(1ull<<b); }
        else      { if ((u32)lane==w-64u) kw1|=(1ull<<b); }
      }
    }
  }
  kept[lane]=kw0;
  if (lane<NWORDS-64) kept[64+lane]=kw1;
}

// ---------------- final outputs -------------------------------------------
__global__ void k_out(const u64* __restrict__ kept, const float4* __restrict__ srawb,
                      const float* __restrict__ ssval, const u32* __restrict__ slab,
                      float* __restrict__ out)
{
  int t=blockIdx.x*blockDim.x+threadIdx.x;
  if (t<M_TOT){
    u32 kb=(u32)((kept[t>>6]>>(t&63))&1ull);
    float kf=kb?1.0f:0.0f;
    float4 b=srawb[t];
    out[4*t+0]=fminf(fmaxf(b.x/1280.0f,0.0f),1.0f)*kf;
    out[4*t+1]=fminf(fmaxf(b.y/1280.0f,0.0f),1.0f)*kf;
    out[4*t+2]=fminf(fmaxf(b.z/1280.0f,0.0f),1.0f)*kf;
    out[4*t+3]=fminf(fmaxf(b.w/1280.0f,0.0f),1.0f)*kf;
    out[19600+t]=ssval[t]*kf;
    out[24500+t]=(float)slab[t];
    out[29400+t]=kf;
  }
}

// ---------------- host ----------------------------------------------------
extern "C" void kernel_launch(void* const* d_in, const int* in_sizes, int n_in,
                              void* d_out, int out_size, void* d_ws, size_t ws_size,
                              hipStream_t stream)
{
  const float* cls[5]={nullptr,nullptr,nullptr,nullptr,nullptr};
  const float* box[5]={nullptr,nullptr,nullptr,nullptr,nullptr};
  static const int clsEl[5]={18432000,4608000,1152000,288000,72000};
  static const int boxEl[5]={921600,230400,57600,14400,3600};
  for (int i=0;i<n_in;i++){
    int sz=in_sizes[i];
    bool done=false;
    for (int l=0;l<5 && !done;l++){
      if (sz==clsEl[l] && !cls[l]){ cls[l]=(const float*)d_in[i]; done=true; }
      else if (sz==boxEl[l] && !box[l]){ box[l]=(const float*)d_in[i]; done=true; }
    }
  }
  unsigned char* ws=(unsigned char*)d_ws;
  u32* cnt   = (u32*)(ws+OFF_CNT);
  u32* flags = (u32*)(ws+OFF_FLAG);
  u64* kept  = (u64*)(ws+OFF_KEPT);
  u64* undec = (u64*)(ws+OFF_UNDEC);
  u32* cand  = (u32*)(ws+OFF_CAND);
  u64* keyA  = (u64*)(ws+OFF_KEY);
  float4* rawbA=(float4*)(ws+OFF_RAWB);
  float4* offbA=(float4*)(ws+OFF_OFFB);
  u32* labA  = (u32*)(ws+OFF_LAB);
  float* svalA=(float*)(ws+OFF_SVAL);
  u32* validA=(u32*)(ws+OFF_VALID);
  u32* order = (u32*)(ws+OFF_ORDER);
  float4* srawb=(float4*)(ws+OFF_SRAWB);
  float4* soffb=(float4*)(ws+OFF_SOFFB);
  u32* slab  = (u32*)(ws+OFF_SLAB);
  float* ssval=(float*)(ws+OFF_SSVAL);
  u32* svalid=(u32*)(ws+OFF_SVALID);
  u32* cempty=(u32*)(ws+OFF_CEMPTY);
  u64* cmat  = (u64*)(ws+OFF_CMAT);
  float* out = (float*)d_out;

  hipMemsetAsync(ws, 0, ZERO_BYTES, stream);

  k_collect<<<dim3(4096),dim3(256),0,stream>>>(cls[0],cls[1],cls[2],cls[3],cls[4],cnt,cand,flags,0);
  k_fbmark <<<dim3(1),dim3(64),0,stream>>>(cnt,flags);
  k_collect<<<dim3(4096),dim3(256),0,stream>>>(cls[0],cls[1],cls[2],cls[3],cls[4],cnt,cand,flags,1);
  k_fbmark <<<dim3(1),dim3(64),0,stream>>>(cnt,flags);
  k_collect<<<dim3(4096),dim3(256),0,stream>>>(cls[0],cls[1],cls[2],cls[3],cls[4],cnt,cand,flags,2);

  k_select<<<dim3(5),dim3(1024),0,stream>>>(cnt,cand,
      (const float4*)box[0],(const float4*)box[1],(const float4*)box[2],
      (const float4*)box[3],(const float4*)box[4],
      keyA,rawbA,offbA,labA,svalA,validA);

  k_rank  <<<dim3(5),dim3(1024),0,stream>>>(keyA,order);
  k_gather<<<dim3(20),dim3(256),0,stream>>>(order,rawbA,offbA,labA,svalA,validA,
                                            srawb,soffb,slab,ssval,svalid);
  k_cmat  <<<dim3(M_TOT),dim3(256),0,stream>>>(soffb,cmat,cempty);
  k_init  <<<dim3(20),dim3(256),0,stream>>>(cempty,svalid,kept,undec);
  k_scan  <<<dim3(1),dim3(64),0,stream>>>(cmat,undec,svalid,kept);
  k_out   <<<dim3(20),dim3(256),0,stream>>>(kept,srawb,ssval,slab,out);
}

// Round 2
// 402.998 us; speedup vs baseline: 2.9174x; 2.9174x over previous
//
#include <hip/hip_runtime.h>
#include <cmath>

typedef unsigned int u32;
typedef unsigned long long u64;

#define NLEV 5
#define M_TOT 4900
#define NWORDS 77          // ceil(4900/64)
#define CSTRIDE 80         // cmat row stride in u64 words (640B)
#define CAP 131072         // candidate capacity per level
#define PAD_M 4928
#define NBLK 2999          // collect blocks (per-level partitioned)
#define LDSQ 1024          // per-block LDS candidate queue

__constant__ int   c_KLVL[5] = {1000,1000,1000,1000,900};
__constant__ int   c_LOFF[5] = {0,1000,2000,3000,4000};
__constant__ int   c_N4[5]   = {4608000,1152000,288000,72000,18000}; // float4s per level
__constant__ int   c_BB[6]   = {0,2250,2813,2954,2990,2999};         // block ranges per level
__constant__ float c_THR[5]  = {1.0f,0.65f,0.30f,-0.15f,-0.60f};

// ---- workspace layout (bytes) ----
constexpr size_t OFF_CNT   = 0;       // u32[8]  per-level candidate counts
constexpr size_t OFF_FLAG  = 64;      // u32[8]  fallback flags
constexpr size_t OFF_KEPT  = 256;     // u64[80] keep bitmask
constexpr size_t OFF_UNDEC = 1024;    // u64[80] undecided bitmask
constexpr size_t ZERO_BYTES= 4096;
constexpr size_t OFF_CAND  = 4096;                               // u32[5*CAP*2]
constexpr size_t OFF_KEY   = OFF_CAND + (size_t)NLEV*CAP*8;      // u64[PAD_M]
constexpr size_t OFF_RAWB  = OFF_KEY   + (size_t)PAD_M*8;        // float4[PAD_M]
constexpr size_t OFF_OFFB  = OFF_RAWB  + (size_t)PAD_M*16;
constexpr size_t OFF_LAB   = OFF_OFFB  + (size_t)PAD_M*16;       // u32
constexpr size_t OFF_SVAL  = OFF_LAB   + (size_t)PAD_M*4;        // f32
constexpr size_t OFF_VALID = OFF_SVAL  + (size_t)PAD_M*4;        // u32
constexpr size_t OFF_ORDER = OFF_VALID + (size_t)PAD_M*4;        // u32
constexpr size_t OFF_SRAWB = OFF_ORDER + (size_t)PAD_M*4;        // float4
constexpr size_t OFF_SOFFB = OFF_SRAWB + (size_t)PAD_M*16;
constexpr size_t OFF_SLAB  = OFF_SOFFB + (size_t)PAD_M*16;       // u32
constexpr size_t OFF_SSVAL = OFF_SLAB  + (size_t)PAD_M*4;        // f32
constexpr size_t OFF_SVALID= OFF_SSVAL + (size_t)PAD_M*4;        // u32
constexpr size_t OFF_CEMPTY= OFF_SVALID+ (size_t)PAD_M*4;        // u32
constexpr size_t OFF_CMAT  = (OFF_CEMPTY + (size_t)PAD_M*4 + 255) & ~(size_t)255;

__device__ __forceinline__ u32 okey(u32 u){
  return (u & 0x80000000u) ? ~u : (u | 0x80000000u);
}

// ---------------- candidate collection (streaming pass over logits) --------
// Block->level partitioning: base pointer is wave-uniform (scalar), 8
// unconditional address-clamped float4 loads in flight per thread, per-block
// LDS aggregation -> ONE global atomic per block (exact counts incl. spill).
__global__ void __launch_bounds__(256)
k_collect(const float* __restrict__ a0, const float* __restrict__ a1,
          const float* __restrict__ a2, const float* __restrict__ a3,
          const float* __restrict__ a4,
          u32* __restrict__ cnt, u32* __restrict__ cand,
          const u32* __restrict__ flags, int round)
{
  const int b = blockIdx.x;
  const int l = (b<c_BB[1])?0:(b<c_BB[2])?1:(b<c_BB[3])?2:(b<c_BB[4])?3:4;
  if (round!=0 && flags[l]==0u) return;
  const float* __restrict__ p = (l==0)?a0:(l==1)?a1:(l==2)?a2:(l==3)?a3:a4;
  const float T = c_THR[l] - 0.8f*(float)round;
  const int n4l = c_N4[l];
  const int lb  = b - c_BB[l];
  const int base4 = lb*2048 + (int)threadIdx.x;

  __shared__ u32 lcnt, gbase;
  __shared__ u32 lbitsA[LDSQ];
  __shared__ u32 lidxA[LDSQ];
  if (threadIdx.x==0) lcnt=0u;
  __syncthreads();

  float4 xs[8];
  int    qi[8];
#pragma unroll
  for (int u=0;u<8;u++){
    int q = base4 + u*256;
    int qc = (q < n4l) ? q : (n4l-1);
    qi[u] = q;
    xs[u] = *(const float4*)(p + (size_t)qc*4u);
  }
  u32* cdL = cand + (size_t)l*CAP*2u;
#pragma unroll
  for (int u=0;u<8;u++){
    if (qi[u] < n4l){
      float v[4]={xs[u].x,xs[u].y,xs[u].z,xs[u].w};
#pragma unroll
      for (int i=0;i<4;i++){
        if (v[i] > T){
          u32 s = atomicAdd(&lcnt,1u);
          u32 bits = __float_as_uint(v[i]);
          u32 idx  = (u32)(qi[u]*4+i);
          if (s < LDSQ){ lbitsA[s]=bits; lidxA[s]=idx; }
          else {
            u32 pp = atomicAdd(&cnt[l],1u);            // rare spill, exact count
            if (pp < CAP){ u32* d=cdL+(size_t)pp*2u; d[0]=bits; d[1]=idx; }
          }
        }
      }
    }
  }
  __syncthreads();
  if (threadIdx.x==0){
    u32 m = min(lcnt,(u32)LDSQ);
    gbase = (m>0u) ? atomicAdd(&cnt[l],m) : 0xFFFFFFFFu;
  }
  __syncthreads();
  u32 m = min(lcnt,(u32)LDSQ);
  for (u32 i=threadIdx.x;i<m;i+=256u){
    u32 pp = gbase + i;
    if (pp < CAP){ u32* d=cdL+(size_t)pp*2u; d[0]=lbitsA[i]; d[1]=lidxA[i]; }
  }
}

__global__ void k_fbmark(u32* cnt, u32* flags){
  int t=threadIdx.x;
  if (t<5){
    u32 need=(cnt[t]<(u32)c_KLVL[t])?1u:0u;
    flags[t]=need;
    if (need) cnt[t]=0u;
  }
}

// ---------------- per-level exact top-k (radix select) + record emit -------
__device__ __forceinline__ void emit_record(int l, int slot, u32 lbits, u32 idx,
    const float4* __restrict__ boxp, u64* keyA, float4* rawbA, float4* offbA,
    u32* labA, float* svalA, u32* validA)
{
#pragma clang fp contract(off)
  float x = __uint_as_float(lbits);
  float s = (float)(1.0 / (1.0 + exp(-(double)x)));
  u32 valid = (s > 0.05f) ? 1u : 0u;
  u32 label = idx % 80u;
  u32 anchor = idx / 80u;
  float4 bx = boxp[anchor];
  float off = (float)label * 1281.0f;   // label * (IMG + 1)
  float4 ob;
  ob.x = bx.x + off; ob.y = bx.y + off; ob.z = bx.z + off; ob.w = bx.w + off;
  u32 pos = ((u32)l << 25) | idx;
  u32 khi = valid ? okey(lbits) : 0u;
  int g = c_LOFF[l] + slot;
  keyA[g]  = ((u64)khi << 32) | (u64)(u32)(~pos);
  rawbA[g] = bx; offbA[g] = ob; labA[g] = label;
  svalA[g] = valid ? s : 0.0f; validA[g] = valid;
}

__device__ __forceinline__ void emit_dummy(int l, int slot,
    u64* keyA, float4* rawbA, float4* offbA, u32* labA, float* svalA, u32* validA)
{
  u32 pos = ((u32)l<<25) | (0x1FFFFFFu - (u32)slot);  // beyond any real idx -> unique
  int g = c_LOFF[l]+slot;
  float4 z; z.x=z.y=z.z=z.w=0.0f;
  keyA[g]=(u64)(u32)(~pos);
  rawbA[g]=z; offbA[g]=z; labA[g]=0u; svalA[g]=0.0f; validA[g]=0u;
}

__global__ void __launch_bounds__(1024)
k_select(const u32* __restrict__ cnt, const u32* __restrict__ cand,
         const float4* b0, const float4* b1, const float4* b2,
         const float4* b3, const float4* b4,
         u64* keyA, float4* rawbA, float4* offbA,
         u32* labA, float* svalA, u32* validA)
{
  const int l = blockIdx.x;
  const float4* boxp = (l==0)?b0:(l==1)?b1:(l==2)?b2:(l==3)?b3:b4;
  const u32* cd = cand + (size_t)l*CAP*2u;
  const int k = c_KLVL[l];
  int count = (int)min(cnt[l], (u32)CAP);

  __shared__ u32 hist[256];
  __shared__ u32 selv, selab;
  __shared__ u32 ntie_s, emit_s;
  __shared__ u32 tieIdx[1024];

  u32 prefix=0u, pmask=0u;
  int kk = (count < k) ? count : k;

  if (count > 0){
    for (int r=0;r<4;r++){
      int shift = 24 - 8*r;
      if (threadIdx.x<256) hist[threadIdx.x]=0u;
      __syncthreads();
      for (int i=threadIdx.x;i<count;i+=1024){
        u32 key = okey(cd[2*(size_t)i]);
        if ((key & pmask)==prefix) atomicAdd(&hist[(key>>shift)&255u],1u);
      }
      __syncthreads();
      if (threadIdx.x<256){
        u32 above=0u;
        for (int v=threadIdx.x+1; v<256; v++) above+=hist[v];
        u32 h=hist[threadIdx.x];
        if ((int)above < kk && kk <= (int)(above+h)){ selv=(u32)threadIdx.x; selab=above; }
      }
      __syncthreads();
      prefix |= selv<<shift; pmask |= 255u<<shift; kk -= (int)selab;
      __syncthreads();
    }
  }
  if (threadIdx.x==0){ ntie_s=0u; emit_s=0u; }
  __syncthreads();

  for (int i=threadIdx.x;i<count;i+=1024){
    u32 lb = cd[2*(size_t)i]; u32 idx = cd[2*(size_t)i+1];
    u32 key = okey(lb);
    if (key > prefix){
      u32 s = atomicAdd(&emit_s,1u);
      if ((int)s < k) emit_record(l,(int)s,lb,idx,boxp,keyA,rawbA,offbA,labA,svalA,validA);
    } else if (key == prefix){
      u32 t = atomicAdd(&ntie_s,1u);
      if (t < 1024u) tieIdx[t]=idx;
    }
  }
  __syncthreads();

  u32 tie_lbits = (prefix & 0x80000000u) ? (prefix ^ 0x80000000u) : ~prefix;
  int nt = (int)min(ntie_s,1024u);
  for (int t=threadIdx.x;t<nt;t+=1024){
    u32 my = tieIdx[t];
    int rank=0;
    for (int t2=0;t2<nt;t2++) rank += (tieIdx[t2] < my) ? 1 : 0;
    if (rank < kk){
      u32 s = atomicAdd(&emit_s,1u);
      if ((int)s<k) emit_record(l,(int)s,tie_lbits,my,boxp,keyA,rawbA,offbA,labA,svalA,validA);
    }
  }
  __syncthreads();
  int em = (int)min(emit_s,(u32)k);
  for (int i=em+threadIdx.x;i<k;i+=1024)
    emit_dummy(l,i,keyA,rawbA,offbA,labA,svalA,validA);
}

// ---------------- global sort via rank-by-counting (keys unique) -----------
__global__ void __launch_bounds__(128)
k_rank(const u64* __restrict__ keyA, u32* __restrict__ order){
  __shared__ u64 sk[M_TOT];
  for (int i=threadIdx.x;i<M_TOT;i+=128) sk[i]=keyA[i];
  __syncthreads();
  int t = blockIdx.x*128+threadIdx.x;
  if (t<M_TOT){
    u64 mk = sk[t];
    int r=0;
#pragma unroll 8
    for (int j=0;j<M_TOT;j++) r += (sk[j]>mk)?1:0;
    order[r]=(u32)t;
  }
}

__global__ void k_gather(const u32* __restrict__ order,
    const float4* __restrict__ rawbA, const float4* __restrict__ offbA,
    const u32* __restrict__ labA, const float* __restrict__ svalA,
    const u32* __restrict__ validA,
    float4* srawb, float4* soffb, u32* slab, float* ssval, u32* svalid)
{
  int t=blockIdx.x*blockDim.x+threadIdx.x;
  if (t<M_TOT){
    u32 slot=min(order[t],(u32)(M_TOT-1));
    srawb[t]=rawbA[slot]; soffb[t]=offbA[slot]; slab[t]=labA[slot];
    ssval[t]=svalA[slot]; svalid[t]=validA[slot];
  }
}

// ---------------- predecessor bitmask matrix (column-major) ----------------
__global__ void __launch_bounds__(256)
k_cmat(const float4* __restrict__ soffb, u64* __restrict__ cmat,
       u32* __restrict__ cempty)
{
#pragma clang fp contract(off)
  int j = blockIdx.x;
  int lane = threadIdx.x & 63;
  int wave = threadIdx.x >> 6;
  __shared__ u32 anyb;
  if (threadIdx.x==0) anyb=0u;
  __syncthreads();
  float4 bj = soffb[j];
  float areaJ = fmaxf(bj.z-bj.x,0.0f)*fmaxf(bj.w-bj.y,0.0f);
  int wmax = j>>6;
  u32 lany=0u;
  for (int w=wave; w<NWORDS; w+=4){
    u64 word=0ull;
    if (w<=wmax){
      int row=w*64+lane;
      bool bit=false;
      if (row<j){
        float4 br = soffb[row];
        float areaR = fmaxf(br.z-br.x,0.0f)*fmaxf(br.w-br.y,0.0f);
        float ltx=fmaxf(br.x,bj.x), lty=fmaxf(br.y,bj.y);
        float rbx=fminf(br.z,bj.z), rby=fminf(br.w,bj.w);
        float wx=fmaxf(rbx-ltx,0.0f), wy=fmaxf(rby-lty,0.0f);
        float inter=wx*wy;
        float den = areaR+areaJ-inter+1e-9f;   // matches ref eval order
        float iou = inter/den;
        bit = iou > 0.6f;
      }
      word = __ballot(bit);
    }
    if (lane==0) cmat[(size_t)j*CSTRIDE+(size_t)w]=word;
    if (word) lany=1u;
  }
  if (lany) atomicOr(&anyb,1u);
  __syncthreads();
  if (threadIdx.x==0) cempty[j] = (anyb==0u)?1u:0u;
}

__global__ void k_init(const u32* __restrict__ cempty, const u32* __restrict__ svalid,
                       u64* kept, u64* undec)
{
  int t=blockIdx.x*blockDim.x+threadIdx.x;
  if (t<M_TOT){
    if (cempty[t]){ if (svalid[t]) atomicOr(&kept[t>>6], 1ull<<(t&63)); }
    else atomicOr(&undec[t>>6], 1ull<<(t&63));
  }
}

// ---------------- sequential greedy resolution of undecided nodes ---------
__global__ void __launch_bounds__(64)
k_scan(const u64* __restrict__ cmat, const u64* __restrict__ undec,
       const u32* __restrict__ svalid, u64* __restrict__ kept)
{
  __shared__ u32 list[M_TOT];
  __shared__ u32 n_s;
  __shared__ u64 uw[NWORDS];
  int lane = threadIdx.x;
  uw[lane]=undec[lane];
  if (lane<NWORDS-64) uw[64+lane]=undec[64+lane];
  __syncthreads();
  if (lane==0){
    u32 n=0;
    for (int w=0;w<NWORDS;w++){
      u64 U=uw[w];
      while(U){ int b=__builtin_ctzll(U); U&=U-1ull; list[n++]=(u32)(w*64+b); }
    }
    n_s=n;
  }
  __syncthreads();
  u32 n=n_s;
  u64 kw0=kept[lane];
  u64 kw1=(lane<NWORDS-64)?kept[64+lane]:0ull;

  u64 ca[4], cb[4]; u32 vv[4];
#pragma unroll
  for (int i=0;i<4;i++){
    ca[i]=0ull; cb[i]=0ull; vv[i]=0u;
    if ((u32)i<n){
      u32 j=list[i]; const u64* cp=cmat+(size_t)j*CSTRIDE;
      ca[i]=cp[lane]; cb[i]=(lane<NWORDS-64)?cp[64+lane]:0ull; vv[i]=svalid[j];
    }
  }
  for (u32 base=0; base<n; base+=4){
#pragma unroll
    for (int i=0;i<4;i++){
      u32 t=base+(u32)i;
      if (t>=n) break;
      u64 c0=ca[i], c1=cb[i]; u32 v=vv[i]; u32 j=list[t];
      u32 tp=t+4;
      if (tp<n){
        u32 j2=list[tp]; const u64* cp=cmat+(size_t)j2*CSTRIDE;
        ca[i]=cp[lane]; cb[i]=(lane<NWORDS-64)?cp[64+lane]:0ull; vv[i]=svalid[j2];
      } else { ca[i]=0ull; cb[i]=0ull; vv[i]=0u; }
      int hit = (((c0&kw0)|(c1&kw1))!=0ull)?1:0;
      bool any = __ballot(hit)!=0ull;
      if (!any && v){
        u32 w=j>>6, b=j&63u;
        if (w<64u){ if ((u32)lane==w) kw0|=(1ull<<b); }
        else      { if ((u32)lane==w-64u) kw1|=(1ull<<b); }
      }
    }
  }
  kept[lane]=kw0;
  if (lane<NWORDS-64) kept[64+lane]=kw1;
}

// ---------------- final outputs -------------------------------------------
__global__ void k_out(const u64* __restrict__ kept, const float4* __restrict__ srawb,
                      const float* __restrict__ ssval, const u32* __restrict__ slab,
                      float* __restrict__ out)
{
  int t=blockIdx.x*blockDim.x+threadIdx.x;
  if (t<M_TOT){
    u32 kb=(u32)((kept[t>>6]>>(t&63))&1ull);
    float kf=kb?1.0f:0.0f;
    float4 b=srawb[t];
    out[4*t+0]=fminf(fmaxf(b.x/1280.0f,0.0f),1.0f)*kf;
    out[4*t+1]=fminf(fmaxf(b.y/1280.0f,0.0f),1.0f)*kf;
    out[4*t+2]=fminf(fmaxf(b.z/1280.0f,0.0f),1.0f)*kf;
    out[4*t+3]=fminf(fmaxf(b.w/1280.0f,0.0f),1.0f)*kf;
    out[19600+t]=ssval[t]*kf;
    out[24500+t]=(float)slab[t];
    out[29400+t]=kf;
  }
}

// ---------------- host ----------------------------------------------------
extern "C" void kernel_launch(void* const* d_in, const int* in_sizes, int n_in,
                              void* d_out, int out_size, void* d_ws, size_t ws_size,
                              hipStream_t stream)
{
  const float* cls[5]={nullptr,nullptr,nullptr,nullptr,nullptr};
  const float* box[5]={nullptr,nullptr,nullptr,nullptr,nullptr};
  static const int clsEl[5]={18432000,4608000,1152000,288000,72000};
  static const int boxEl[5]={921600,230400,57600,14400,3600};
  for (int i=0;i<n_in;i++){
    int sz=in_sizes[i];
    bool done=false;
    for (int l=0;l<5 && !done;l++){
      if (sz==clsEl[l] && !cls[l]){ cls[l]=(const float*)d_in[i]; done=true; }
      else if (sz==boxEl[l] && !box[l]){ box[l]=(const float*)d_in[i]; done=true; }
    }
  }
  unsigned char* ws=(unsigned char*)d_ws;
  u32* cnt   = (u32*)(ws+OFF_CNT);
  u32* flags = (u32*)(ws+OFF_FLAG);
  u64* kept  = (u64*)(ws+OFF_KEPT);
  u64* undec = (u64*)(ws+OFF_UNDEC);
  u32* cand  = (u32*)(ws+OFF_CAND);
  u64* keyA  = (u64*)(ws+OFF_KEY);
  float4* rawbA=(float4*)(ws+OFF_RAWB);
  float4* offbA=(float4*)(ws+OFF_OFFB);
  u32* labA  = (u32*)(ws+OFF_LAB);
  float* svalA=(float*)(ws+OFF_SVAL);
  u32* validA=(u32*)(ws+OFF_VALID);
  u32* order = (u32*)(ws+OFF_ORDER);
  float4* srawb=(float4*)(ws+OFF_SRAWB);
  float4* soffb=(float4*)(ws+OFF_SOFFB);
  u32* slab  = (u32*)(ws+OFF_SLAB);
  float* ssval=(float*)(ws+OFF_SSVAL);
  u32* svalid=(u32*)(ws+OFF_SVALID);
  u32* cempty=(u32*)(ws+OFF_CEMPTY);
  u64* cmat  = (u64*)(ws+OFF_CMAT);
  float* out = (float*)d_out;

  hipMemsetAsync(ws, 0, ZERO_BYTES, stream);

  k_collect<<<dim3(NBLK),dim3(256),0,stream>>>(cls[0],cls[1],cls[2],cls[3],cls[4],cnt,cand,flags,0);
  k_fbmark <<<dim3(1),dim3(64),0,stream>>>(cnt,flags);
  k_collect<<<dim3(NBLK),dim3(256),0,stream>>>(cls[0],cls[1],cls[2],cls[3],cls[4],cnt,cand,flags,1);
  k_fbmark <<<dim3(1),dim3(64),0,stream>>>(cnt,flags);
  k_collect<<<dim3(NBLK),dim3(256),0,stream>>>(cls[0],cls[1],cls[2],cls[3],cls[4],cnt,cand,flags,2);

  k_select<<<dim3(5),dim3(1024),0,stream>>>(cnt,cand,
      (const float4*)box[0],(const float4*)box[1],(const float4*)box[2],
      (const float4*)box[3],(const float4*)box[4],
      keyA,rawbA,offbA,labA,svalA,validA);

  k_rank  <<<dim3(39),dim3(128),0,stream>>>(keyA,order);
  k_gather<<<dim3(20),dim3(256),0,stream>>>(order,rawbA,offbA,labA,svalA,validA,
                                            srawb,soffb,slab,ssval,svalid);
  k_cmat  <<<dim3(M_TOT),dim3(256),0,stream>>>(soffb,cmat,cempty);
  k_init  <<<dim3(20),dim3(256),0,stream>>>(cempty,svalid,kept,undec);
  k_scan  <<<dim3(1),dim3(64),0,stream>>>(cmat,undec,svalid,kept);
  k_out   <<<dim3(20),dim3(256),0,stream>>>(kept,srawb,ssval,slab,out);
}

// Round 3
// 313.511 us; speedup vs baseline: 3.7501x; 1.2854x over previous
//
#include <hip/hip_runtime.h>
#include <cmath>

typedef unsigned int u32;
typedef unsigned long long u64;

#define NLEV 5
#define M_TOT 4900
#define NWORDS 77          // ceil(4900/64)
#define CSTRIDE 80         // cmat row stride in u64 words (640B)
#define CAP 131072         // candidate capacity per level
#define PAD_M 4928
#define NBLK 2999          // collect blocks (per-level partitioned)
#define LDSQ 1024          // per-block LDS candidate queue

__constant__ int   c_KLVL[5] = {1000,1000,1000,1000,900};
__constant__ int   c_LOFF[5] = {0,1000,2000,3000,4000};
__constant__ int   c_N4[5]   = {4608000,1152000,288000,72000,18000}; // float4s per level
__constant__ int   c_BB[6]   = {0,2250,2813,2954,2990,2999};         // block ranges per level
__constant__ float c_THR[5]  = {1.0f,0.65f,0.30f,-0.15f,-0.60f};

// ---- workspace layout (bytes) ----
constexpr size_t OFF_CNT   = 0;       // u32[8]  per-level candidate counts
constexpr size_t OFF_FLAG  = 64;      // u32[8]  fallback flags
constexpr size_t OFF_KEPT  = 256;     // u64[96] keep bitmask
constexpr size_t OFF_UNDEC = 1024;    // u64[96] undecided bitmask
constexpr size_t ZERO_BYTES= 4096;
constexpr size_t OFF_CAND  = 4096;                               // u32[5*CAP*2]
constexpr size_t OFF_KEY   = OFF_CAND + (size_t)NLEV*CAP*8;      // u64[PAD_M]
constexpr size_t OFF_RAWB  = OFF_KEY   + (size_t)PAD_M*8;        // float4[PAD_M]
constexpr size_t OFF_OFFB  = OFF_RAWB  + (size_t)PAD_M*16;
constexpr size_t OFF_LAB   = OFF_OFFB  + (size_t)PAD_M*16;       // u32
constexpr size_t OFF_SVAL  = OFF_LAB   + (size_t)PAD_M*4;        // f32
constexpr size_t OFF_VALID = OFF_SVAL  + (size_t)PAD_M*4;        // u32
constexpr size_t OFF_ORDER = OFF_VALID + (size_t)PAD_M*4;        // u32
constexpr size_t OFF_SRAWB = OFF_ORDER + (size_t)PAD_M*4;        // float4
constexpr size_t OFF_SOFFB = OFF_SRAWB + (size_t)PAD_M*16;
constexpr size_t OFF_SLAB  = OFF_SOFFB + (size_t)PAD_M*16;       // u32
constexpr size_t OFF_SSVAL = OFF_SLAB  + (size_t)PAD_M*4;        // f32
constexpr size_t OFF_SVALID= OFF_SSVAL + (size_t)PAD_M*4;        // u32
constexpr size_t OFF_CEMPTY= OFF_SVALID+ (size_t)PAD_M*4;        // u32 (unused, kept for layout)
constexpr size_t OFF_CMAT  = (OFF_CEMPTY + (size_t)PAD_M*4 + 255) & ~(size_t)255;

__device__ __forceinline__ u32 okey(u32 u){
  return (u & 0x80000000u) ? ~u : (u | 0x80000000u);
}

// ---------------- candidate collection (streaming pass over logits) --------
__global__ void __launch_bounds__(256)
k_collect(const float* __restrict__ a0, const float* __restrict__ a1,
          const float* __restrict__ a2, const float* __restrict__ a3,
          const float* __restrict__ a4,
          u32* __restrict__ cnt, u32* __restrict__ cand,
          const u32* __restrict__ flags, int round)
{
  const int b = blockIdx.x;
  const int l = (b<c_BB[1])?0:(b<c_BB[2])?1:(b<c_BB[3])?2:(b<c_BB[4])?3:4;
  if (round!=0 && flags[l]==0u) return;
  const float* __restrict__ p = (l==0)?a0:(l==1)?a1:(l==2)?a2:(l==3)?a3:a4;
  const float T = c_THR[l] - 0.8f*(float)round;
  const int n4l = c_N4[l];
  const int lb  = b - c_BB[l];
  const int base4 = lb*2048 + (int)threadIdx.x;

  __shared__ u32 lcnt, gbase;
  __shared__ u32 lbitsA[LDSQ];
  __shared__ u32 lidxA[LDSQ];
  if (threadIdx.x==0) lcnt=0u;
  __syncthreads();

  float4 xs[8];
  int    qi[8];
#pragma unroll
  for (int u=0;u<8;u++){
    int q = base4 + u*256;
    int qc = (q < n4l) ? q : (n4l-1);
    qi[u] = q;
    xs[u] = *(const float4*)(p + (size_t)qc*4u);
  }
  u32* cdL = cand + (size_t)l*CAP*2u;
#pragma unroll
  for (int u=0;u<8;u++){
    if (qi[u] < n4l){
      float v[4]={xs[u].x,xs[u].y,xs[u].z,xs[u].w};
#pragma unroll
      for (int i=0;i<4;i++){
        if (v[i] > T){
          u32 s = atomicAdd(&lcnt,1u);
          u32 bits = __float_as_uint(v[i]);
          u32 idx  = (u32)(qi[u]*4+i);
          if (s < LDSQ){ lbitsA[s]=bits; lidxA[s]=idx; }
          else {
            u32 pp = atomicAdd(&cnt[l],1u);            // rare spill, exact count
            if (pp < CAP){ u32* d=cdL+(size_t)pp*2u; d[0]=bits; d[1]=idx; }
          }
        }
      }
    }
  }
  __syncthreads();
  if (threadIdx.x==0){
    u32 m = min(lcnt,(u32)LDSQ);
    gbase = (m>0u) ? atomicAdd(&cnt[l],m) : 0xFFFFFFFFu;
  }
  __syncthreads();
  u32 m = min(lcnt,(u32)LDSQ);
  for (u32 i=threadIdx.x;i<m;i+=256u){
    u32 pp = gbase + i;
    if (pp < CAP){ u32* d=cdL+(size_t)pp*2u; d[0]=lbitsA[i]; d[1]=lidxA[i]; }
  }
}

__global__ void k_fbmark(u32* cnt, u32* flags){
  int t=threadIdx.x;
  if (t<5){
    u32 need=(cnt[t]<(u32)c_KLVL[t])?1u:0u;
    flags[t]=need;
    if (need) cnt[t]=0u;
  }
}

// ---------------- per-level exact top-k (radix select) + record emit -------
__device__ __forceinline__ void emit_record(int l, int slot, u32 lbits, u32 idx,
    const float4* __restrict__ boxp, u64* keyA, float4* rawbA, float4* offbA,
    u32* labA, float* svalA, u32* validA)
{
#pragma clang fp contract(off)
  float x = __uint_as_float(lbits);
  float s = (float)(1.0 / (1.0 + exp(-(double)x)));
  u32 valid = (s > 0.05f) ? 1u : 0u;
  u32 label = idx % 80u;
  u32 anchor = idx / 80u;
  float4 bx = boxp[anchor];
  float off = (float)label * 1281.0f;   // label * (IMG + 1)
  float4 ob;
  ob.x = bx.x + off; ob.y = bx.y + off; ob.z = bx.z + off; ob.w = bx.w + off;
  u32 pos = ((u32)l << 25) | idx;
  u32 khi = valid ? okey(lbits) : 0u;
  int g = c_LOFF[l] + slot;
  keyA[g]  = ((u64)khi << 32) | (u64)(u32)(~pos);
  rawbA[g] = bx; offbA[g] = ob; labA[g] = label;
  svalA[g] = valid ? s : 0.0f; validA[g] = valid;
}

__device__ __forceinline__ void emit_dummy(int l, int slot,
    u64* keyA, float4* rawbA, float4* offbA, u32* labA, float* svalA, u32* validA)
{
  u32 pos = ((u32)l<<25) | (0x1FFFFFFu - (u32)slot);  // beyond any real idx -> unique
  int g = c_LOFF[l]+slot;
  float4 z; z.x=z.y=z.z=z.w=0.0f;
  keyA[g]=(u64)(u32)(~pos);
  rawbA[g]=z; offbA[g]=z; labA[g]=0u; svalA[g]=0.0f; validA[g]=0u;
}

__global__ void __launch_bounds__(1024)
k_select(const u32* __restrict__ cnt, const u32* __restrict__ cand,
         const float4* b0, const float4* b1, const float4* b2,
         const float4* b3, const float4* b4,
         u64* keyA, float4* rawbA, float4* offbA,
         u32* labA, float* svalA, u32* validA)
{
  const int l = blockIdx.x;
  const float4* boxp = (l==0)?b0:(l==1)?b1:(l==2)?b2:(l==3)?b3:b4;
  const u32* cd = cand + (size_t)l*CAP*2u;
  const int k = c_KLVL[l];
  int count = (int)min(cnt[l], (u32)CAP);

  __shared__ u32 hist[256];
  __shared__ u32 selv, selab;
  __shared__ u32 ntie_s, emit_s;
  __shared__ u32 tieIdx[1024];

  u32 prefix=0u, pmask=0u;
  int kk = (count < k) ? count : k;

  if (count > 0){
    for (int r=0;r<4;r++){
      int shift = 24 - 8*r;
      if (threadIdx.x<256) hist[threadIdx.x]=0u;
      __syncthreads();
      for (int i=threadIdx.x;i<count;i+=1024){
        u32 key = okey(cd[2*(size_t)i]);
        if ((key & pmask)==prefix) atomicAdd(&hist[(key>>shift)&255u],1u);
      }
      __syncthreads();
      if (threadIdx.x<256){
        u32 above=0u;
        for (int v=threadIdx.x+1; v<256; v++) above+=hist[v];
        u32 h=hist[threadIdx.x];
        if ((int)above < kk && kk <= (int)(above+h)){ selv=(u32)threadIdx.x; selab=above; }
      }
      __syncthreads();
      prefix |= selv<<shift; pmask |= 255u<<shift; kk -= (int)selab;
      __syncthreads();
    }
  }
  if (threadIdx.x==0){ ntie_s=0u; emit_s=0u; }
  __syncthreads();

  for (int i=threadIdx.x;i<count;i+=1024){
    u32 lb = cd[2*(size_t)i]; u32 idx = cd[2*(size_t)i+1];
    u32 key = okey(lb);
    if (key > prefix){
      u32 s = atomicAdd(&emit_s,1u);
      if ((int)s < k) emit_record(l,(int)s,lb,idx,boxp,keyA,rawbA,offbA,labA,svalA,validA);
    } else if (key == prefix){
      u32 t = atomicAdd(&ntie_s,1u);
      if (t < 1024u) tieIdx[t]=idx;
    }
  }
  __syncthreads();

  u32 tie_lbits = (prefix & 0x80000000u) ? (prefix ^ 0x80000000u) : ~prefix;
  int nt = (int)min(ntie_s,1024u);
  for (int t=threadIdx.x;t<nt;t+=1024){
    u32 my = tieIdx[t];
    int rank=0;
    for (int t2=0;t2<nt;t2++) rank += (tieIdx[t2] < my) ? 1 : 0;
    if (rank < kk){
      u32 s = atomicAdd(&emit_s,1u);
      if ((int)s<k) emit_record(l,(int)s,tie_lbits,my,boxp,keyA,rawbA,offbA,labA,svalA,validA);
    }
  }
  __syncthreads();
  int em = (int)min(emit_s,(u32)k);
  for (int i=em+threadIdx.x;i<k;i+=1024)
    emit_dummy(l,i,keyA,rawbA,offbA,labA,svalA,validA);
}

// ---------------- global sort via rank-by-counting (keys unique) -----------
// block b ranks i in [b*64, b*64+64): one i per lane; 4 waves each count a
// j-quarter via LDS broadcast reads, lane-wise combine.
__global__ void __launch_bounds__(256)
k_rank(const u64* __restrict__ keyA, u32* __restrict__ order){
  __shared__ u64 sk[M_TOT];
  __shared__ u32 part[3][64];
  for (int i=threadIdx.x;i<M_TOT;i+=256) sk[i]=keyA[i];
  __syncthreads();
  int lane = threadIdx.x & 63;
  int wave = threadIdx.x >> 6;
  int i = blockIdx.x*64 + lane;
  u64 mk = sk[(i<M_TOT)?i:0];
  int j0 = wave*1225;
  u32 r=0;
#pragma unroll 5
  for (int j=j0;j<j0+1225;j++) r += (sk[j]>mk)?1u:0u;
  if (wave) part[wave-1][lane]=r;
  __syncthreads();
  if (wave==0 && i<M_TOT){
    r += part[0][lane]+part[1][lane]+part[2][lane];
    order[r]=(u32)i;
  }
}

__global__ void k_gather(const u32* __restrict__ order,
    const float4* __restrict__ rawbA, const float4* __restrict__ offbA,
    const u32* __restrict__ labA, const float* __restrict__ svalA,
    const u32* __restrict__ validA,
    float4* srawb, float4* soffb, u32* slab, float* ssval, u32* svalid)
{
  int t=blockIdx.x*blockDim.x+threadIdx.x;
  if (t<M_TOT){
    u32 slot=min(order[t],(u32)(M_TOT-1));
    srawb[t]=rawbA[slot]; soffb[t]=offbA[slot]; slab[t]=labA[slot];
    ssval[t]=svalA[slot]; svalid[t]=validA[slot];
  }
}

// ------- predecessor bitmask matrix (column-major) + kept/undec init -------
__global__ void __launch_bounds__(256)
k_cmat(const float4* __restrict__ soffb, u64* __restrict__ cmat,
       const u32* __restrict__ svalid, u64* __restrict__ kept,
       u64* __restrict__ undec)
{
#pragma clang fp contract(off)
  int j = blockIdx.x;
  int lane = threadIdx.x & 63;
  int wave = threadIdx.x >> 6;
  __shared__ u32 anyb;
  if (threadIdx.x==0) anyb=0u;
  __syncthreads();
  float4 bj = soffb[j];
  float areaJ = fmaxf(bj.z-bj.x,0.0f)*fmaxf(bj.w-bj.y,0.0f);
  int wmax = j>>6;
  u32 lany=0u;
  for (int w=wave; w<NWORDS; w+=4){
    u64 word=0ull;
    if (w<=wmax){
      int row=w*64+lane;
      bool bit=false;
      if (row<j){
        float4 br = soffb[row];
        float areaR = fmaxf(br.z-br.x,0.0f)*fmaxf(br.w-br.y,0.0f);
        float ltx=fmaxf(br.x,bj.x), lty=fmaxf(br.y,bj.y);
        float rbx=fminf(br.z,bj.z), rby=fminf(br.w,bj.w);
        float wx=fmaxf(rbx-ltx,0.0f), wy=fmaxf(rby-lty,0.0f);
        float inter=wx*wy;
        float den = areaR+areaJ-inter+1e-9f;   // matches ref eval order
        float iou = inter/den;
        bit = iou > 0.6f;
      }
      word = __ballot(bit);
    }
    if (lane==0) cmat[(size_t)j*CSTRIDE+(size_t)w]=word;
    if (word) lany=1u;
  }
  if (lany) atomicOr(&anyb,1u);
  __syncthreads();
  if (threadIdx.x==0){
    if (anyb==0u){ if (svalid[j]) atomicOr(&kept[j>>6], 1ull<<(j&63)); }
    else atomicOr(&undec[j>>6], 1ull<<(j&63));
  }
}

// ------- greedy resolution, decomposed by class (cross-class IoU == 0) -----
__global__ void __launch_bounds__(64)
k_scan(const u64* __restrict__ cmat, const u64* __restrict__ undec,
       const u32* __restrict__ svalid, const u32* __restrict__ slab,
       u64* __restrict__ kept)
{
  const u32 c = blockIdx.x;             // class id 0..79
  __shared__ u32 list[M_TOT];           // node | cls<<13 | valid<<20
  __shared__ unsigned short clist[M_TOT];
  __shared__ u32 n_s, nc_s;
  __shared__ u64 uw[NWORDS];
  int lane = threadIdx.x;
  uw[lane]=undec[lane];
  if (lane<NWORDS-64) uw[64+lane]=undec[64+lane];
  __syncthreads();
  if (lane==0){
    u32 n=0;
    for (int w=0;w<NWORDS;w++){
      u64 U=uw[w];
      while(U){ int b=__builtin_ctzll(U); U&=U-1ull; list[n++]=(u32)(w*64+b); }
    }
    n_s=n;
  }
  __syncthreads();
  u32 n=n_s;
  for (u32 i=lane;i<n;i+=64u){
    u32 node=list[i];
    list[i] = node | (slab[node]<<13) | ((svalid[node]&1u)<<20);
  }
  __syncthreads();
  if (lane==0){
    u32 nc=0;
    for (u32 i=0;i<n;i++){
      u32 e=list[i];
      if (((e>>13)&0x7Fu)==c) clist[nc++]=(unsigned short)(e & 0x1FFFu) , list[M_TOT-1-nc]=0u, clist[nc-1]=(unsigned short)(e&0x1FFFu), list[nc-1+0]=list[nc-1+0]; // keep simple
    }
    nc_s=nc;
  }
  __syncthreads();
  u32 nc=nc_s;
  if (nc==0u) return;
  // validity per class node (re-read from packed list is gone; use svalid)
  u64 kw0=kept[lane];
  u64 kw1=(lane<NWORDS-64)?kept[64+lane]:0ull;
  u64 nk0=0ull, nk1=0ull;
  for (u32 t=0;t<nc;t++){
    u32 j=(u32)clist[t];
    const u64* cp=cmat+(size_t)j*CSTRIDE;
    u64 c0=cp[lane];
    u64 c1=(lane<NWORDS-64)?cp[64+lane]:0ull;
    u32 v=svalid[j];
    int hit = (((c0&kw0)|(c1&kw1))!=0ull)?1:0;
    bool any = __ballot(hit)!=0ull;
    if (!any && v){
      u32 w=j>>6, b=j&63u;
      if (w<64u){ if ((u32)lane==w){ kw0|=(1ull<<b); nk0|=(1ull<<b);} }
      else      { if ((u32)lane==(w-64u)){ kw1|=(1ull<<b); nk1|=(1ull<<b);} }
    }
  }
  if (nk0) atomicOr(&kept[lane],nk0);
  if (lane<NWORDS-64 && nk1) atomicOr(&kept[64+lane],nk1);
}

// ---------------- final outputs -------------------------------------------
__global__ void k_out(const u64* __restrict__ kept, const float4* __restrict__ srawb,
                      const float* __restrict__ ssval, const u32* __restrict__ slab,
                      float* __restrict__ out)
{
  int t=blockIdx.x*blockDim.x+threadIdx.x;
  if (t<M_TOT){
    u32 kb=(u32)((kept[t>>6]>>(t&63))&1ull);
    float kf=kb?1.0f:0.0f;
    float4 b=srawb[t];
    out[4*t+0]=fminf(fmaxf(b.x/1280.0f,0.0f),1.0f)*kf;
    out[4*t+1]=fminf(fmaxf(b.y/1280.0f,0.0f),1.0f)*kf;
    out[4*t+2]=fminf(fmaxf(b.z/1280.0f,0.0f),1.0f)*kf;
    out[4*t+3]=fminf(fmaxf(b.w/1280.0f,0.0f),1.0f)*kf;
    out[19600+t]=ssval[t]*kf;
    out[24500+t]=(float)slab[t];
    out[29400+t]=kf;
  }
}

// ---------------- host ----------------------------------------------------
extern "C" void kernel_launch(void* const* d_in, const int* in_sizes, int n_in,
                              void* d_out, int out_size, void* d_ws, size_t ws_size,
                              hipStream_t stream)
{
  const float* cls[5]={nullptr,nullptr,nullptr,nullptr,nullptr};
  const float* box[5]={nullptr,nullptr,nullptr,nullptr,nullptr};
  static const int clsEl[5]={18432000,4608000,1152000,288000,72000};
  static const int boxEl[5]={921600,230400,57600,14400,3600};
  for (int i=0;i<n_in;i++){
    int sz=in_sizes[i];
    bool done=false;
    for (int l=0;l<5 && !done;l++){
      if (sz==clsEl[l] && !cls[l]){ cls[l]=(const float*)d_in[i]; done=true; }
      else if (sz==boxEl[l] && !box[l]){ box[l]=(const float*)d_in[i]; done=true; }
    }
  }
  unsigned char* ws=(unsigned char*)d_ws;
  u32* cnt   = (u32*)(ws+OFF_CNT);
  u32* flags = (u32*)(ws+OFF_FLAG);
  u64* kept  = (u64*)(ws+OFF_KEPT);
  u64* undec = (u64*)(ws+OFF_UNDEC);
  u32* cand  = (u32*)(ws+OFF_CAND);
  u64* keyA  = (u64*)(ws+OFF_KEY);
  float4* rawbA=(float4*)(ws+OFF_RAWB);
  float4* offbA=(float4*)(ws+OFF_OFFB);
  u32* labA  = (u32*)(ws+OFF_LAB);
  float* svalA=(float*)(ws+OFF_SVAL);
  u32* validA=(u32*)(ws+OFF_VALID);
  u32* order = (u32*)(ws+OFF_ORDER);
  float4* srawb=(float4*)(ws+OFF_SRAWB);
  float4* soffb=(float4*)(ws+OFF_SOFFB);
  u32* slab  = (u32*)(ws+OFF_SLAB);
  float* ssval=(float*)(ws+OFF_SSVAL);
  u32* svalid=(u32*)(ws+OFF_SVALID);
  u64* cmat  = (u64*)(ws+OFF_CMAT);
  float* out = (float*)d_out;

  hipMemsetAsync(ws, 0, ZERO_BYTES, stream);

  k_collect<<<dim3(NBLK),dim3(256),0,stream>>>(cls[0],cls[1],cls[2],cls[3],cls[4],cnt,cand,flags,0);
  k_fbmark <<<dim3(1),dim3(64),0,stream>>>(cnt,flags);
  k_collect<<<dim3(NBLK),dim3(256),0,stream>>>(cls[0],cls[1],cls[2],cls[3],cls[4],cnt,cand,flags,1);
  k_fbmark <<<dim3(1),dim3(64),0,stream>>>(cnt,flags);
  k_collect<<<dim3(NBLK),dim3(256),0,stream>>>(cls[0],cls[1],cls[2],cls[3],cls[4],cnt,cand,flags,2);

  k_select<<<dim3(5),dim3(1024),0,stream>>>(cnt,cand,
      (const float4*)box[0],(const float4*)box[1],(const float4*)box[2],
      (const float4*)box[3],(const float4*)box[4],
      keyA,rawbA,offbA,labA,svalA,validA);

  k_rank  <<<dim3(77),dim3(256),0,stream>>>(keyA,order);
  k_gather<<<dim3(20),dim3(256),0,stream>>>(order,rawbA,offbA,labA,svalA,validA,
                                            srawb,soffb,slab,ssval,svalid);
  k_cmat  <<<dim3(M_TOT),dim3(256),0,stream>>>(soffb,cmat,svalid,kept,undec);
  k_scan  <<<dim3(80),dim3(64),0,stream>>>(cmat,undec,svalid,slab,kept);
  k_out   <<<dim3(20),dim3(256),0,stream>>>(kept,srawb,ssval,slab,out);
}